// Round 12
// baseline (470.404 us; speedup 1.0000x reference)
//
#include <hip/hip_runtime.h>
#include <hip/hip_cooperative_groups.h>
#include <cstdint>
#include <cstddef>

namespace cg = cooperative_groups;

// ---------------- problem constants ----------------
#define E_EDGES     524288
#define N_TOT       16384      // total nodes (8 graphs x 2048)
#define HID         64
#define B_GR        8
#define KTOT        131072     // NPG*HID, FC1 inner dim
#define NJ          2048       // FC1 output width
#define MAXN        15
#define SLOTS       96         // fixed CSR capacity; deg ~ Binom(E,1/N): mean 32, sigma 5.7

// FC1 tiling: one block = full 2048-wide row (512 thr x float4), KC rows
#define KC          256
#define NCHUNK      512        // KTOT/KC

typedef float vf4 __attribute__((ext_vector_type(4)));   // native clang vector (nontemporal-ok)

// ---------------- workspace layout (bytes) ----------------
#define OFF_CURSOR  0x0u         // 64 KB (16384 int)
#define OFF_DIS     0x10000u     // 64 KB (16384 f32)
#define OFF_SLOTS   0x20000u     // 3.15 MB (16384 x 96 ushort)
#define OFF_H1      0x320000u    // 4 MB
#define OFF_H2      0x720000u    // 4 MB
#define OFF_TMP     0xB20000u    // 512 KB (8 x 16384 f32)
#define OFF_PART    0xBA0000u    // 33.55 MB (512 x 8 x 2048 f32)

__device__ __forceinline__ float selu_f(float x) {
    const float scale = 1.0507009873554805f;
    const float alpha = 1.6732632423543772f;
    return x > 0.0f ? scale * x : scale * alpha * expm1f(x);
}

// ---- cooperative: zero cursor + fixed-slot CSR scatter + dis ----
// 1024 blocks x 256 thr; bounds(256,4) caps VGPR at 128 -> 4 blocks/CU co-resident.
__launch_bounds__(256, 4)
__global__ void graph_build_kernel(const int* __restrict__ src, const int* __restrict__ dst,
                                   int* __restrict__ cursor,
                                   unsigned short* __restrict__ slots,
                                   float* __restrict__ dis) {
    cg::grid_group grid = cg::this_grid();
    const int gid = blockIdx.x * 256 + threadIdx.x;   // 0..262143
    // S0: zero cursors
    if (gid < N_TOT) cursor[gid] = 0;
    grid.sync();
    // S1: scatter, 2 edges/thread (2*262144 == E_EDGES)
    {
        int e0 = gid, e1 = gid + 262144;
        int s0 = src[e0], d0 = dst[e0];
        int p0 = atomicAdd(&cursor[d0], 1);
        slots[d0 * SLOTS + p0] = (unsigned short)s0;
        int s1 = src[e1], d1 = dst[e1];
        int p1 = atomicAdd(&cursor[d1], 1);
        slots[d1 * SLOTS + p1] = (unsigned short)s1;
    }
    grid.sync();
    // S2: dis = rsqrt(deg+1)
    if (gid < N_TOT) dis[gid] = rsqrtf((float)(cursor[gid] + 1));
}

// ---- layer 1 fused: slot gather with on-the-fly x@W1 (linearity) ----
// h1[d][c] = selu( dis_d*sum_s dis_s*(x[s]@W1)_c + dis_d^2*(x[d]@W1)_c + b1[c] )
__launch_bounds__(256)
__global__ void gather1_kernel(const int* __restrict__ cursor,
                               const unsigned short* __restrict__ slots,
                               const float* __restrict__ dis, const float* __restrict__ x,
                               const float* __restrict__ W1, const float* __restrict__ b1,
                               float* __restrict__ h1) {
    int node = blockIdx.x * 4 + (threadIdx.x >> 6);
    int c = threadIdx.x & 63;
    float w0 = W1[c], w1 = W1[64 + c], w2 = W1[128 + c], w3 = W1[192 + c];
    int deg = cursor[node];
    float ds = dis[node];
    const unsigned short* sl = slots + node * SLOTS;
    float acc = 0.f;
    int i = 0;
    for (; i + 1 < deg; i += 2) {
        int sa = sl[i], sb = sl[i + 1];
        float da = dis[sa], db = dis[sb];
        const float4 xa = *reinterpret_cast<const float4*>(x + (size_t)sa * 4);
        const float4 xb = *reinterpret_cast<const float4*>(x + (size_t)sb * 4);
        float xwa = fmaf(xa.x, w0, fmaf(xa.y, w1, fmaf(xa.z, w2, xa.w * w3)));
        float xwb = fmaf(xb.x, w0, fmaf(xb.y, w1, fmaf(xb.z, w2, xb.w * w3)));
        acc = fmaf(xwa, da, acc);
        acc = fmaf(xwb, db, acc);
    }
    if (i < deg) {
        int sa = sl[i];
        float da = dis[sa];
        const float4 xa = *reinterpret_cast<const float4*>(x + (size_t)sa * 4);
        float xwa = fmaf(xa.x, w0, fmaf(xa.y, w1, fmaf(xa.z, w2, xa.w * w3)));
        acc = fmaf(xwa, da, acc);
    }
    const float4 xd = *reinterpret_cast<const float4*>(x + (size_t)node * 4);
    float xwd = fmaf(xd.x, w0, fmaf(xd.y, w1, fmaf(xd.z, w2, xd.w * w3)));
    float val = fmaf(acc, ds, xwd * ds * ds) + b1[c];
    h1[(size_t)node * HID + c] = selu_f(val);
}

// ---- fused layer-2: slot gather (agg2 in registers) + W2 matmul + selu ----
__launch_bounds__(256)
__global__ void agg2h2_kernel(const int* __restrict__ cursor,
                              const unsigned short* __restrict__ slots,
                              const float* __restrict__ dis, const float* __restrict__ h1,
                              const float* __restrict__ W2, const float* __restrict__ b2,
                              float* __restrict__ h2) {
    __shared__ float w2s[HID * HID];      // 16 KB
    for (int idx = threadIdx.x; idx < HID * HID; idx += 256) w2s[idx] = W2[idx];
    __syncthreads();

    int node = blockIdx.x * 4 + (threadIdx.x >> 6);
    int c = threadIdx.x & 63;
    int deg = cursor[node];
    float ds = dis[node];
    const unsigned short* sl = slots + node * SLOTS;
    float acc = 0.f;
    int i = 0;
    for (; i + 3 < deg; i += 4) {
        int sa = sl[i], sb = sl[i + 1], sc = sl[i + 2], sd = sl[i + 3];
        float da = dis[sa], db = dis[sb], dc = dis[sc], dd = dis[sd];
        acc = fmaf(h1[(size_t)sa * HID + c], da, acc);
        acc = fmaf(h1[(size_t)sb * HID + c], db, acc);
        acc = fmaf(h1[(size_t)sc * HID + c], dc, acc);
        acc = fmaf(h1[(size_t)sd * HID + c], dd, acc);
    }
    for (; i < deg; ++i) {
        int sa = sl[i];
        acc = fmaf(h1[(size_t)sa * HID + c], dis[sa], acc);
    }
    size_t base = (size_t)node * HID + c;
    float inv = acc * ds + h1[base] * ds * ds;   // agg2 + h1*dis^2, channel c

    float o = b2[c];
    #pragma unroll
    for (int cc = 0; cc < HID; ++cc)
        o = fmaf(__shfl(inv, cc, 64), w2s[cc * HID + c], o);
    h2[base] = selu_f(o);
}

// ---- FC1: block = 512 thr x float4 = full 2048-wide row; KC contiguous rows.
// kk-tiles of 4, unroll 4 (16 nontemporal loads in flight).
__launch_bounds__(512, 4)
__global__ void fc1_kernel(const float* __restrict__ h2, const float* __restrict__ Wf1,
                           float* __restrict__ partials) {
    __shared__ float hch[B_GR * KC];      // 8 KB, [b][kk]
    const int chunk = blockIdx.x;         // 0..NCHUNK-1
    const int k0 = chunk * KC;
    for (int idx = threadIdx.x; idx < B_GR * KC; idx += 512) {
        int b = idx >> 8;                 // KC = 256
        int kk = idx & (KC - 1);
        hch[idx] = h2[(size_t)b * KTOT + k0 + kk];
    }
    __syncthreads();
    vf4 acc[B_GR];
    #pragma unroll
    for (int b = 0; b < B_GR; ++b) acc[b] = (vf4)(0.f);
    const int j = threadIdx.x * 4;
    const float* wp = Wf1 + (size_t)k0 * NJ + j;
    #pragma unroll 4
    for (int kk4 = 0; kk4 < KC / 4; ++kk4) {
        vf4 w0 = __builtin_nontemporal_load(reinterpret_cast<const vf4*>(wp));
        vf4 w1 = __builtin_nontemporal_load(reinterpret_cast<const vf4*>(wp + NJ));
        vf4 w2 = __builtin_nontemporal_load(reinterpret_cast<const vf4*>(wp + 2 * NJ));
        vf4 w3 = __builtin_nontemporal_load(reinterpret_cast<const vf4*>(wp + 3 * NJ));
        wp += 4 * NJ;
        #pragma unroll
        for (int b = 0; b < B_GR; ++b) {
            const vf4 hv = *reinterpret_cast<const vf4*>(&hch[b * KC + kk4 * 4]);
            acc[b] += w0 * hv.x;
            acc[b] += w1 * hv.y;
            acc[b] += w2 * hv.z;
            acc[b] += w3 * hv.w;
        }
    }
    float* pp = partials + (size_t)chunk * (B_GR * NJ) + j;
    #pragma unroll
    for (int b = 0; b < B_GR; ++b)
        *reinterpret_cast<vf4*>(pp + (size_t)b * NJ) = acc[b];
}

// ---- reduce stage 1: 512 chunks -> 8 group-partials ----
__global__ void fc1_reduce1_kernel(const float* __restrict__ partials, float* __restrict__ tmp) {
    int idx = blockIdx.x * 256 + threadIdx.x;   // 0..16383
    int g = blockIdx.y;                         // 0..7  (64 chunks each)
    float s = 0.f;
    const float* p = partials + (size_t)(g * 64) * (B_GR * NJ) + idx;
    #pragma unroll 8
    for (int c = 0; c < 64; ++c) { s += *p; p += B_GR * NJ; }
    tmp[(size_t)g * (B_GR * NJ) + idx] = s;
}

// ---- FC2 (+ final reduce + FC1 bias & selu): out[b][m] ----
__global__ void fc2_kernel(const float* __restrict__ tmp, const float* __restrict__ bf1,
                           const float* __restrict__ Wf2, const float* __restrict__ bf2,
                           float* __restrict__ out) {
    int b = blockIdx.x;
    int t = threadIdx.x;  // 64
    float acc[MAXN];
    #pragma unroll
    for (int m = 0; m < MAXN; ++m) acc[m] = 0.f;
    for (int j = t; j < NJ; j += 64) {
        size_t o = (size_t)b * NJ + j;
        float s = 0.f;
        #pragma unroll
        for (int g = 0; g < 8; ++g) s += tmp[(size_t)g * (B_GR * NJ) + o];
        float zv = selu_f(s + bf1[j]);
        const float* wr = Wf2 + (size_t)j * MAXN;
        #pragma unroll
        for (int m = 0; m < MAXN; ++m) acc[m] = fmaf(zv, wr[m], acc[m]);
    }
    #pragma unroll
    for (int m = 0; m < MAXN; ++m) {
        float v = acc[m];
        for (int off = 32; off > 0; off >>= 1) v += __shfl_down(v, off, 64);
        if (t == 0) out[b * MAXN + m] = v + bf2[m];
    }
}

extern "C" void kernel_launch(void* const* d_in, const int* in_sizes, int n_in,
                              void* d_out, int out_size, void* d_ws, size_t ws_size,
                              hipStream_t stream) {
    const float* x    = (const float*)d_in[0];
    const int*   ei   = (const int*)d_in[1];      // int32 (JAX x64 disabled)
    const float* W1   = (const float*)d_in[2];
    const float* b1   = (const float*)d_in[3];
    const float* W2   = (const float*)d_in[4];
    const float* b2   = (const float*)d_in[5];
    const float* Wf1  = (const float*)d_in[6];
    const float* bf1  = (const float*)d_in[7];
    const float* Wf2  = (const float*)d_in[8];
    const float* bf2  = (const float*)d_in[9];
    float* out = (float*)d_out;

    const int* src = ei;
    const int* dst = ei + E_EDGES;

    char* ws = (char*)d_ws;
    int*            cursor = (int*)            (ws + OFF_CURSOR);
    float*          dis    = (float*)          (ws + OFF_DIS);
    unsigned short* slots  = (unsigned short*) (ws + OFF_SLOTS);
    float*          h1     = (float*)          (ws + OFF_H1);
    float*          h2     = (float*)          (ws + OFF_H2);
    float*          tmp    = (float*)          (ws + OFF_TMP);
    float*          parts  = (float*)          (ws + OFF_PART);

    void* gargs[] = { (void*)&src, (void*)&dst, (void*)&cursor,
                      (void*)&slots, (void*)&dis };
    hipLaunchCooperativeKernel((void*)graph_build_kernel, dim3(1024), dim3(256),
                               gargs, 0, stream);

    gather1_kernel<<<N_TOT / 4, 256, 0, stream>>>(cursor, slots, dis, x, W1, b1, h1);
    agg2h2_kernel<<<N_TOT / 4, 256, 0, stream>>>(cursor, slots, dis, h1, W2, b2, h2);
    fc1_kernel <<<NCHUNK, 512, 0, stream>>>(h2, Wf1, parts);
    fc1_reduce1_kernel<<<dim3(64, 8), 256, 0, stream>>>(parts, tmp);
    fc2_kernel <<<B_GR, 64, 0, stream>>>(tmp, bf1, Wf2, bf2, out);
}

// Round 13
// 295.996 us; speedup vs baseline: 1.5892x; 1.5892x over previous
//
#include <hip/hip_runtime.h>
#include <cstdint>
#include <cstddef>

// ---------------- problem constants ----------------
#define E_EDGES     524288
#define N_TOT       16384      // total nodes (8 graphs x 2048)
#define HID         64
#define B_GR        8
#define KTOT        131072     // NPG*HID, FC1 inner dim
#define NJ          2048       // FC1 output width
#define MAXN        15
#define SLOTS       96         // fixed CSR capacity; deg ~ Binom(E,1/N): mean 32, sigma 5.7

// FC1 tiling: one block = full 2048-wide row (512 thr x float4), KC rows
#define KC          256
#define NCHUNK      512        // KTOT/KC

typedef float vf4 __attribute__((ext_vector_type(4)));   // native clang vector (nontemporal-ok)

// ---------------- workspace layout (bytes) ----------------
#define OFF_CURSOR  0x0u         // 64 KB (16384 int) -- the only memset
#define OFF_DIS     0x10000u     // 64 KB (16384 f32)
#define OFF_SLOTS   0x20000u     // 3.15 MB (16384 x 96 ushort)
#define OFF_H1      0x320000u    // 4 MB
#define OFF_H2      0x720000u    // 4 MB
#define OFF_TMP     0xB20000u    // 512 KB (8 x 16384 f32)
#define OFF_PART    0xBA0000u    // 33.55 MB (512 x 8 x 2048 f32)

__device__ __forceinline__ float selu_f(float x) {
    const float scale = 1.0507009873554805f;
    const float alpha = 1.6732632423543772f;
    return x > 0.0f ? scale * x : scale * alpha * expm1f(x);
}

// ---- build fixed-slot CSR (ushort cols): cursor RMW + store; cursor ends as in-degree ----
__global__ void scatter_kernel(const int* __restrict__ src, const int* __restrict__ dst,
                               int* __restrict__ cursor, unsigned short* __restrict__ slots) {
    int e = blockIdx.x * 256 + threadIdx.x;
    if (e >= E_EDGES) return;
    int s = src[e], d = dst[e];
    int pos = atomicAdd(&cursor[d], 1);
    slots[d * SLOTS + pos] = (unsigned short)s;
}

// ---- dis[i] = rsqrt(deg+1) ----
__global__ void dis_kernel(const int* __restrict__ cursor, float* __restrict__ dis) {
    int i = blockIdx.x * 256 + threadIdx.x;
    if (i < N_TOT) dis[i] = rsqrtf((float)(cursor[i] + 1));
}

// ---- layer 1 fused: slot gather with on-the-fly x@W1 (linearity) ----
// h1[d][c] = selu( dis_d*sum_s dis_s*(x[s]@W1)_c + dis_d^2*(x[d]@W1)_c + b1[c] )
__launch_bounds__(256)
__global__ void gather1_kernel(const int* __restrict__ cursor,
                               const unsigned short* __restrict__ slots,
                               const float* __restrict__ dis, const float* __restrict__ x,
                               const float* __restrict__ W1, const float* __restrict__ b1,
                               float* __restrict__ h1) {
    int node = blockIdx.x * 4 + (threadIdx.x >> 6);
    int c = threadIdx.x & 63;
    float w0 = W1[c], w1 = W1[64 + c], w2 = W1[128 + c], w3 = W1[192 + c];
    int deg = cursor[node];
    float ds = dis[node];
    const unsigned short* sl = slots + node * SLOTS;
    float acc = 0.f;
    int i = 0;
    for (; i + 1 < deg; i += 2) {
        int sa = sl[i], sb = sl[i + 1];
        float da = dis[sa], db = dis[sb];
        const float4 xa = *reinterpret_cast<const float4*>(x + (size_t)sa * 4);
        const float4 xb = *reinterpret_cast<const float4*>(x + (size_t)sb * 4);
        float xwa = fmaf(xa.x, w0, fmaf(xa.y, w1, fmaf(xa.z, w2, xa.w * w3)));
        float xwb = fmaf(xb.x, w0, fmaf(xb.y, w1, fmaf(xb.z, w2, xb.w * w3)));
        acc = fmaf(xwa, da, acc);
        acc = fmaf(xwb, db, acc);
    }
    if (i < deg) {
        int sa = sl[i];
        float da = dis[sa];
        const float4 xa = *reinterpret_cast<const float4*>(x + (size_t)sa * 4);
        float xwa = fmaf(xa.x, w0, fmaf(xa.y, w1, fmaf(xa.z, w2, xa.w * w3)));
        acc = fmaf(xwa, da, acc);
    }
    const float4 xd = *reinterpret_cast<const float4*>(x + (size_t)node * 4);
    float xwd = fmaf(xd.x, w0, fmaf(xd.y, w1, fmaf(xd.z, w2, xd.w * w3)));
    float val = fmaf(acc, ds, xwd * ds * ds) + b1[c];
    h1[(size_t)node * HID + c] = selu_f(val);
}

// ---- fused layer-2: slot gather (agg2 in registers) + W2 matmul + selu ----
__launch_bounds__(256)
__global__ void agg2h2_kernel(const int* __restrict__ cursor,
                              const unsigned short* __restrict__ slots,
                              const float* __restrict__ dis, const float* __restrict__ h1,
                              const float* __restrict__ W2, const float* __restrict__ b2,
                              float* __restrict__ h2) {
    __shared__ float w2s[HID * HID];      // 16 KB
    for (int idx = threadIdx.x; idx < HID * HID; idx += 256) w2s[idx] = W2[idx];
    __syncthreads();

    int node = blockIdx.x * 4 + (threadIdx.x >> 6);
    int c = threadIdx.x & 63;
    int deg = cursor[node];
    float ds = dis[node];
    const unsigned short* sl = slots + node * SLOTS;
    float acc = 0.f;
    int i = 0;
    for (; i + 3 < deg; i += 4) {
        int sa = sl[i], sb = sl[i + 1], sc = sl[i + 2], sd = sl[i + 3];
        float da = dis[sa], db = dis[sb], dc = dis[sc], dd = dis[sd];
        acc = fmaf(h1[(size_t)sa * HID + c], da, acc);
        acc = fmaf(h1[(size_t)sb * HID + c], db, acc);
        acc = fmaf(h1[(size_t)sc * HID + c], dc, acc);
        acc = fmaf(h1[(size_t)sd * HID + c], dd, acc);
    }
    for (; i < deg; ++i) {
        int sa = sl[i];
        acc = fmaf(h1[(size_t)sa * HID + c], dis[sa], acc);
    }
    size_t base = (size_t)node * HID + c;
    float inv = acc * ds + h1[base] * ds * ds;   // agg2 + h1*dis^2, channel c

    float o = b2[c];
    #pragma unroll
    for (int cc = 0; cc < HID; ++cc)
        o = fmaf(__shfl(inv, cc, 64), w2s[cc * HID + c], o);
    h2[base] = selu_f(o);
}

// ---- FC1: block = 512 thr x float4 = full 2048-wide row; KC contiguous rows.
// kk-tiles of 4, unroll 4 (16 nontemporal loads in flight).
__launch_bounds__(512, 4)
__global__ void fc1_kernel(const float* __restrict__ h2, const float* __restrict__ Wf1,
                           float* __restrict__ partials) {
    __shared__ float hch[B_GR * KC];      // 8 KB, [b][kk]
    const int chunk = blockIdx.x;         // 0..NCHUNK-1
    const int k0 = chunk * KC;
    for (int idx = threadIdx.x; idx < B_GR * KC; idx += 512) {
        int b = idx >> 8;                 // KC = 256
        int kk = idx & (KC - 1);
        hch[idx] = h2[(size_t)b * KTOT + k0 + kk];
    }
    __syncthreads();
    vf4 acc[B_GR];
    #pragma unroll
    for (int b = 0; b < B_GR; ++b) acc[b] = (vf4)(0.f);
    const int j = threadIdx.x * 4;
    const float* wp = Wf1 + (size_t)k0 * NJ + j;
    #pragma unroll 4
    for (int kk4 = 0; kk4 < KC / 4; ++kk4) {
        vf4 w0 = __builtin_nontemporal_load(reinterpret_cast<const vf4*>(wp));
        vf4 w1 = __builtin_nontemporal_load(reinterpret_cast<const vf4*>(wp + NJ));
        vf4 w2 = __builtin_nontemporal_load(reinterpret_cast<const vf4*>(wp + 2 * NJ));
        vf4 w3 = __builtin_nontemporal_load(reinterpret_cast<const vf4*>(wp + 3 * NJ));
        wp += 4 * NJ;
        #pragma unroll
        for (int b = 0; b < B_GR; ++b) {
            const vf4 hv = *reinterpret_cast<const vf4*>(&hch[b * KC + kk4 * 4]);
            acc[b] += w0 * hv.x;
            acc[b] += w1 * hv.y;
            acc[b] += w2 * hv.z;
            acc[b] += w3 * hv.w;
        }
    }
    float* pp = partials + (size_t)chunk * (B_GR * NJ) + j;
    #pragma unroll
    for (int b = 0; b < B_GR; ++b)
        *reinterpret_cast<vf4*>(pp + (size_t)b * NJ) = acc[b];
}

// ---- reduce stage 1: 512 chunks -> 8 group-partials ----
__global__ void fc1_reduce1_kernel(const float* __restrict__ partials, float* __restrict__ tmp) {
    int idx = blockIdx.x * 256 + threadIdx.x;   // 0..16383
    int g = blockIdx.y;                         // 0..7  (64 chunks each)
    float s = 0.f;
    const float* p = partials + (size_t)(g * 64) * (B_GR * NJ) + idx;
    #pragma unroll 8
    for (int c = 0; c < 64; ++c) { s += *p; p += B_GR * NJ; }
    tmp[(size_t)g * (B_GR * NJ) + idx] = s;
}

// ---- FC2 (+ final reduce + FC1 bias & selu): out[b][m] ----
__global__ void fc2_kernel(const float* __restrict__ tmp, const float* __restrict__ bf1,
                           const float* __restrict__ Wf2, const float* __restrict__ bf2,
                           float* __restrict__ out) {
    int b = blockIdx.x;
    int t = threadIdx.x;  // 64
    float acc[MAXN];
    #pragma unroll
    for (int m = 0; m < MAXN; ++m) acc[m] = 0.f;
    for (int j = t; j < NJ; j += 64) {
        size_t o = (size_t)b * NJ + j;
        float s = 0.f;
        #pragma unroll
        for (int g = 0; g < 8; ++g) s += tmp[(size_t)g * (B_GR * NJ) + o];
        float zv = selu_f(s + bf1[j]);
        const float* wr = Wf2 + (size_t)j * MAXN;
        #pragma unroll
        for (int m = 0; m < MAXN; ++m) acc[m] = fmaf(zv, wr[m], acc[m]);
    }
    #pragma unroll
    for (int m = 0; m < MAXN; ++m) {
        float v = acc[m];
        for (int off = 32; off > 0; off >>= 1) v += __shfl_down(v, off, 64);
        if (t == 0) out[b * MAXN + m] = v + bf2[m];
    }
}

extern "C" void kernel_launch(void* const* d_in, const int* in_sizes, int n_in,
                              void* d_out, int out_size, void* d_ws, size_t ws_size,
                              hipStream_t stream) {
    const float* x    = (const float*)d_in[0];
    const int*   ei   = (const int*)d_in[1];      // int32 (JAX x64 disabled)
    const float* W1   = (const float*)d_in[2];
    const float* b1   = (const float*)d_in[3];
    const float* W2   = (const float*)d_in[4];
    const float* b2   = (const float*)d_in[5];
    const float* Wf1  = (const float*)d_in[6];
    const float* bf1  = (const float*)d_in[7];
    const float* Wf2  = (const float*)d_in[8];
    const float* bf2  = (const float*)d_in[9];
    float* out = (float*)d_out;

    const int* src = ei;
    const int* dst = ei + E_EDGES;

    char* ws = (char*)d_ws;
    int*            cursor = (int*)            (ws + OFF_CURSOR);
    float*          dis    = (float*)          (ws + OFF_DIS);
    unsigned short* slots  = (unsigned short*) (ws + OFF_SLOTS);
    float*          h1     = (float*)          (ws + OFF_H1);
    float*          h2     = (float*)          (ws + OFF_H2);
    float*          tmp    = (float*)          (ws + OFF_TMP);
    float*          parts  = (float*)          (ws + OFF_PART);

    (void)hipMemsetAsync(cursor, 0, N_TOT * sizeof(int), stream);

    scatter_kernel<<<E_EDGES / 256, 256, 0, stream>>>(src, dst, cursor, slots);
    dis_kernel<<<N_TOT / 256, 256, 0, stream>>>(cursor, dis);
    gather1_kernel<<<N_TOT / 4, 256, 0, stream>>>(cursor, slots, dis, x, W1, b1, h1);
    agg2h2_kernel<<<N_TOT / 4, 256, 0, stream>>>(cursor, slots, dis, h1, W2, b2, h2);
    fc1_kernel <<<NCHUNK, 512, 0, stream>>>(h2, Wf1, parts);
    fc1_reduce1_kernel<<<dim3(64, 8), 256, 0, stream>>>(parts, tmp);
    fc2_kernel <<<B_GR, 64, 0, stream>>>(tmp, bf1, Wf2, bf2, out);
}